// Round 1
// baseline (47.555 us; speedup 1.0000x reference)
//
#include <hip/hip_runtime.h>

// DynamicMaskHead: per-instance 3-layer 1x1-conv MLP over [rel_xy, feats] at
// 112x200, then AdelaiDet aligned_bilinear 2x upsample to [n,1,224,400].
// Fused single kernel: logit tile staged in LDS, never hits HBM.

#define IN_C   8
#define CHN    8
#define Hh     112
#define Ww     200
#define HWp    (Hh * Ww)
#define OH     224
#define OW     400
#define TY     16          // output rows per block
#define RL     9           // logit rows needed per tile (TY/2 + 1)
#define NTILES (OH / TY)   // 14
#define NPARAMS 169

// param layout per instance (169 floats):
// w0 [8][10] @0, w1 [8][8] @80, w2 [8] @144, b0 [8] @152, b1 [8] @160, b2 @168

__global__ __launch_bounds__(256)
void dmh_fused_kernel(const float* __restrict__ feats,      // [4][8][112][200]
                      const float* __restrict__ params,     // [n][169]
                      const float* __restrict__ iloc,       // [n][2]
                      const float* __restrict__ soi_tab,    // [5]
                      const int*   __restrict__ im_inds,    // [n]
                      const int*   __restrict__ fpn_levels, // [n]
                      float* __restrict__ out)              // [n][224][400]
{
    __shared__ float lds[RL][Ww];   // 9*200*4 = 7.2 KB

    const int bid  = blockIdx.x;
    const int inst = bid / NTILES;
    const int ty   = bid - inst * NTILES;
    const int y0   = ty * TY;
    const int r_lo = (y0 > 0 ? (y0 - 1) : 0) >> 1;   // first logit row of tile
    const int tid  = threadIdx.x;

    const float* __restrict__ wp = params + inst * NPARAMS;  // block-uniform -> s_load
    const float soi    = soi_tab[fpn_levels[inst]];
    const float inv_s  = 1.0f / soi;
    const float ix     = iloc[inst * 2 + 0];
    const float iy     = iloc[inst * 2 + 1];
    const float* __restrict__ fb = feats + (size_t)im_inds[inst] * (IN_C * HWp);

    // ---------------- phase 1: logits for rows [r_lo, r_lo+RL) ----------------
    // 4 pixels per thread-group-iteration; W=200 divisible by 4, rows never split.
    const int NG = (RL * Ww) / 4;   // 450
    for (int g = tid; g < NG; g += 256) {
        const int rr = g / (Ww / 4);            // 0..8
        const int c4 = (g - rr * (Ww / 4)) * 4; // 0..196
        const int r  = r_lo + rr;               // <= 111 by construction
        const float* fp = fb + r * Ww + c4;

        float fv[IN_C][4];
        #pragma unroll
        for (int ch = 0; ch < IN_C; ch++) {
            const float4 t = *reinterpret_cast<const float4*>(fp + ch * HWp);
            fv[ch][0] = t.x; fv[ch][1] = t.y; fv[ch][2] = t.z; fv[ch][3] = t.w;
        }
        const float in1 = (iy - (float)(r * 8 + 4)) * inv_s;
        float in0[4];
        #pragma unroll
        for (int k = 0; k < 4; k++)
            in0[k] = (ix - (float)((c4 + k) * 8 + 4)) * inv_s;

        float h0[CHN][4];
        #pragma unroll
        for (int o = 0; o < CHN; o++) {
            const float b = wp[152 + o];
            #pragma unroll
            for (int k = 0; k < 4; k++) {
                float a = fmaf(wp[o * 10 + 0], in0[k], b);
                a = fmaf(wp[o * 10 + 1], in1, a);
                #pragma unroll
                for (int i = 0; i < IN_C; i++)
                    a = fmaf(wp[o * 10 + 2 + i], fv[i][k], a);
                h0[o][k] = fmaxf(a, 0.0f);
            }
        }
        float h1[CHN][4];
        #pragma unroll
        for (int o = 0; o < CHN; o++) {
            const float b = wp[160 + o];
            #pragma unroll
            for (int k = 0; k < 4; k++) {
                float a = b;
                #pragma unroll
                for (int i = 0; i < CHN; i++)
                    a = fmaf(wp[80 + o * 8 + i], h0[i][k], a);
                h1[o][k] = fmaxf(a, 0.0f);
            }
        }
        float res[4];
        #pragma unroll
        for (int k = 0; k < 4; k++) {
            float a = wp[168];
            #pragma unroll
            for (int i = 0; i < CHN; i++)
                a = fmaf(wp[144 + i], h1[i][k], a);
            res[k] = a;
        }
        *reinterpret_cast<float4*>(&lds[rr][c4]) =
            make_float4(res[0], res[1], res[2], res[3]);
    }
    __syncthreads();

    // ---------------- phase 2: aligned 2x bilinear, write 16x400 tile ----------
    // out[y][x] = interp[max(y-1,0)][max(x-1,0)], axis weights {1} even / {.5,.5} odd
    float* __restrict__ ob = out + (size_t)inst * (OH * OW);
    const int NQ = (TY * OW) / 4;   // 1600 groups of 4 output px
    for (int q = tid; q < NQ; q += 256) {
        const int dy = q / (OW / 4);            // 0..15
        const int gx = q - dy * (OW / 4);       // 0..99
        const int x  = gx * 4;
        const int y  = y0 + dy;
        const int i  = (y > 0 ? y - 1 : 0);
        const int rr0 = (i >> 1) - r_lo;
        const int r1g = (i >> 1) + (i & 1);
        const int rr1 = (r1g > Hh - 1 ? Hh - 1 : r1g) - r_lo;
        const float wy1 = (i & 1) ? 0.5f : 0.0f;
        const float wy0 = 1.0f - wy1;

        const int cx  = x >> 1;                 // 0..198 (x even)
        const int cm1 = (cx > 0 ? cx - 1 : 0);
        // cols needed: cm1, cx, cx+1 (cx+1 <= 199 always)
        const float a_m = lds[rr0][cm1], a_0 = lds[rr0][cx], a_p = lds[rr0][cx + 1];
        const float b_m = lds[rr1][cm1], b_0 = lds[rr1][cx], b_p = lds[rr1][cx + 1];
        const float Rm = wy0 * a_m + wy1 * b_m;
        const float R0 = wy0 * a_0 + wy1 * b_0;
        const float Rp = wy0 * a_p + wy1 * b_p;

        float4 o4;
        o4.x = 0.5f * (Rm + R0);   // x+0: odd j (or clamped at x=0 where Rm==R0)
        o4.y = R0;                 // x+1: exact col cx
        o4.z = 0.5f * (R0 + Rp);   // x+2: odd j
        o4.w = Rp;                 // x+3: exact col cx+1
        *reinterpret_cast<float4*>(&ob[y * OW + x]) = o4;
    }
}

extern "C" void kernel_launch(void* const* d_in, const int* in_sizes, int n_in,
                              void* d_out, int out_size, void* d_ws, size_t ws_size,
                              hipStream_t stream) {
    const float* mask_feats = (const float*)d_in[0];
    const float* params     = (const float*)d_in[1];
    const float* iloc       = (const float*)d_in[2];
    const float* soi        = (const float*)d_in[3];
    const int*   im_inds    = (const int*)d_in[4];
    const int*   fpn        = (const int*)d_in[5];
    // d_in[6] = mask_feat_stride (=8), baked into the kernel constants.
    float* out = (float*)d_out;

    const int n_inst = in_sizes[4];           // 200
    dim3 grid(n_inst * NTILES);               // 2800 blocks
    dim3 block(256);
    hipLaunchKernelGGL(dmh_fused_kernel, grid, block, 0, stream,
                       mask_feats, params, iloc, soi, im_inds, fpn, out);
}